// Round 5
// baseline (201.823 us; speedup 1.0000x reference)
//
#include <hip/hip_runtime.h>
#include <hip/hip_bf16.h>

typedef __bf16 bf16_t;
typedef bf16_t bf16x8 __attribute__((ext_vector_type(8)));
typedef bf16_t bf16x4 __attribute__((ext_vector_type(4)));
typedef float f32x4 __attribute__((ext_vector_type(4)));

#define NODE_DIM 512
#define COND_DIM 512
#define EDGE_DIM 128

// workspace layout (bytes)
#define WS_WN   0x000000   // v_node bf16: 128x512 = 128 KB
#define WS_WC   0x020000   // w_film bf16 (B^T perm): 256x128 = 64 KB
#define WS_SC   0x030000   // scale_node: 128 f32
#define WS_GA   0x031000   // gamma: 16x128 f32
#define WS_BE   0x033000   // beta: 16x128 f32
#define WS_P    0x040000   // P: 4096x256 bf16 = 2 MB

__device__ __forceinline__ bf16x8 cvt8(float4 a, float4 b) {
    bf16x8 v;
    v[0] = (bf16_t)a.x; v[1] = (bf16_t)a.y; v[2] = (bf16_t)a.z; v[3] = (bf16_t)a.w;
    v[4] = (bf16_t)b.x; v[5] = (bf16_t)b.y; v[6] = (bf16_t)b.z; v[7] = (bf16_t)b.w;
    return v;
}

// ---------------------------------------------------------------------------
// Kernel 1 (prep): weight bf16 conversions + weight-norm scales + gamma/beta.
// blocks [0,32):    v_node -> Wn_bf16  (64K elems, 8/thread)
// blocks [32,48):   w_film -> Wc_bf16 permuted: row n<128 = w_film[n][0:128],
//                   row n>=128 = w_film[n-128][128:256]
// blocks [48,80):   scale_node[e] = g_node[e]/||v_node[e]||  (wave per row)
// blocks [80,1104): gamma/beta = cond_feats @ weight_norm(v_cond)^T + b_cond
// ---------------------------------------------------------------------------
__global__ __launch_bounds__(256) void prep_kernel(
    const float* __restrict__ cond_feats,
    const float* __restrict__ v_node, const float* __restrict__ g_node,
    const float* __restrict__ v_cond, const float* __restrict__ g_cond,
    const float* __restrict__ b_cond, const float* __restrict__ w_film,
    char* __restrict__ ws)
{
    bf16_t* Wn = (bf16_t*)(ws + WS_WN);
    bf16_t* Wc = (bf16_t*)(ws + WS_WC);
    float* scale_node = (float*)(ws + WS_SC);
    float* gamma = (float*)(ws + WS_GA);
    float* beta  = (float*)(ws + WS_BE);

    int t = threadIdx.x;
    int bid = blockIdx.x;
    int lane = t & 63, wv = t >> 6;

    if (bid < 32) {
        size_t idx = ((size_t)bid * 256 + t) * 8;
        float4 a = ((const float4*)(v_node + idx))[0];
        float4 b = ((const float4*)(v_node + idx))[1];
        *(bf16x8*)(Wn + idx) = cvt8(a, b);
    } else if (bid < 48) {
        int u = (bid - 32) * 256 + t;        // 0..4095, 8 elems each
        int n = u >> 4;                      // 0..255
        int ko = (u & 15) * 8;               // 0..120
        const float* src = (n < 128) ? (w_film + (size_t)n * 256 + ko)
                                     : (w_film + (size_t)(n - 128) * 256 + 128 + ko);
        float4 a = ((const float4*)src)[0];
        float4 b = ((const float4*)src)[1];
        *(bf16x8*)(Wc + (size_t)n * 128 + ko) = cvt8(a, b);
    } else if (bid < 80) {
        int id = (bid - 48) * 4 + wv;        // 0..127
        const float* vn = v_node + (size_t)id * NODE_DIM + lane * 8;
        float sq = 0.f;
#pragma unroll
        for (int i = 0; i < 2; i++) {
            float4 v4 = ((const float4*)vn)[i];
            sq += v4.x * v4.x + v4.y * v4.y + v4.z * v4.z + v4.w * v4.w;
        }
#pragma unroll
        for (int o = 32; o > 0; o >>= 1) sq += __shfl_xor(sq, o);
        if (lane == 0) scale_node[id] = g_node[id] * rsqrtf(sq);
    } else {
        int id = (bid - 80) * 4 + wv;        // 0..4095
        int b = id >> 8, n = id & 255;
        const float* cf = cond_feats + b * COND_DIM + lane * 8;
        const float* vc = v_cond + (size_t)n * COND_DIM + lane * 8;
        float dot = 0.f, sq = 0.f;
#pragma unroll
        for (int i = 0; i < 2; i++) {
            float4 c4 = ((const float4*)cf)[i];
            float4 v4 = ((const float4*)vc)[i];
            dot += c4.x * v4.x + c4.y * v4.y + c4.z * v4.z + c4.w * v4.w;
            sq  += v4.x * v4.x + v4.y * v4.y + v4.z * v4.z + v4.w * v4.w;
        }
#pragma unroll
        for (int o = 32; o > 0; o >>= 1) {
            dot += __shfl_xor(dot, o);
            sq  += __shfl_xor(sq, o);
        }
        if (lane == 0) {
            float val = dot * (g_cond[n] * rsqrtf(sq)) + b_cond[n];
            if (n < 128) gamma[b * 128 + n] = val + 1.0f;
            else         beta[b * 128 + (n - 128)] = val;
        }
    }
}

// ---------------------------------------------------------------------------
// Kernel 2 (gemm): 256 blocks x 16-row M-tiles, 4 waves.
// A fragments load DIRECTLY from node_feats fp32 in MFMA layout (32 B/lane,
// 2x float4), converted to bf16 in-register; W fragments from bf16 ws arrays.
// No barriers in the K-loops -> all loads independent, compiler pipelines.
// Phase 1: nodes16x128 = relu((A16x512 @ Wn^T)*scale + b_node) -> LDS bf16.
// Phase 2: P16x256 = nodes @ Wc^T; epilogue transposes via LDS -> 16 B stores.
// ---------------------------------------------------------------------------
__global__ __launch_bounds__(256) void gemm_kernel(
    const float* __restrict__ node_feats, const float* __restrict__ b_node,
    char* __restrict__ ws)
{
    const bf16_t* Wn = (const bf16_t*)(ws + WS_WN);
    const bf16_t* Wc = (const bf16_t*)(ws + WS_WC);
    const float* scale_node = (const float*)(ws + WS_SC);
    bf16_t* P = (bf16_t*)(ws + WS_P);

    __shared__ __attribute__((aligned(16))) bf16_t N_s[16 * 136];
    __shared__ __attribute__((aligned(16))) float  T_s[4][16][68];

    int t = threadIdx.x;
    int lane = t & 63, w = t >> 6;
    int r16 = lane & 15, half = lane >> 4;
    int m0 = blockIdx.x * 16;

    f32x4 zero4 = {0.f, 0.f, 0.f, 0.f};

    // ---- phase 1: wave w covers output cols [w*32, w*32+32) ----
    f32x4 acc0 = zero4, acc1 = zero4;
    {
        const float*  aptr = node_feats + (size_t)(m0 + r16) * NODE_DIM + half * 8;
        const bf16_t* bptr = Wn + (size_t)(w * 32 + r16) * NODE_DIM + half * 8;
#pragma unroll
        for (int ks = 0; ks < 16; ks++) {
            float4 a0 = ((const float4*)(aptr + ks * 32))[0];
            float4 a1 = ((const float4*)(aptr + ks * 32))[1];
            bf16x8 af = cvt8(a0, a1);
            bf16x8 b0 = *(const bf16x8*)(bptr + ks * 32);
            bf16x8 b1 = *(const bf16x8*)(bptr + 16 * NODE_DIM + ks * 32);
            acc0 = __builtin_amdgcn_mfma_f32_16x16x32_bf16(af, b0, acc0, 0, 0, 0);
            acc1 = __builtin_amdgcn_mfma_f32_16x16x32_bf16(af, b1, acc1, 0, 0, 0);
        }
    }
    // epilogue 1: C/D layout col=lane&15, row=(lane>>4)*4+reg -> N_s[row][col]
    {
        int rbase = half * 4;
#pragma unroll
        for (int j = 0; j < 2; j++) {
            int col = w * 32 + j * 16 + r16;
            float s = scale_node[col], bb = b_node[col];
            f32x4 a = j ? acc1 : acc0;
#pragma unroll
            for (int r = 0; r < 4; r++) {
                float v = fmaxf(a[r] * s + bb, 0.f);
                N_s[(rbase + r) * 136 + col] = (bf16_t)v;
            }
        }
    }
    __syncthreads();

    // ---- phase 2: wave w covers output cols [w*64, w*64+64) ----
    f32x4 acc2[4];
#pragma unroll
    for (int i = 0; i < 4; i++) acc2[i] = zero4;
    {
        const bf16_t* bptr = Wc + (size_t)(w * 64 + r16) * 128 + half * 8;
#pragma unroll
        for (int ks = 0; ks < 4; ks++) {
            bf16x8 af = *(const bf16x8*)&N_s[r16 * 136 + ks * 32 + half * 8];
#pragma unroll
            for (int j = 0; j < 4; j++) {
                bf16x8 bf = *(const bf16x8*)(bptr + j * 16 * 128 + ks * 32);
                acc2[j] = __builtin_amdgcn_mfma_f32_16x16x32_bf16(af, bf, acc2[j], 0, 0, 0);
            }
        }
    }
    // epilogue 2: transpose via LDS, then 16-B coalesced bf16 stores to P
    {
        int rbase = half * 4;
#pragma unroll
        for (int j = 0; j < 4; j++) {
            int col = j * 16 + r16;
#pragma unroll
            for (int r = 0; r < 4; r++) T_s[w][rbase + r][col] = acc2[j][r];
        }
    }
    __syncthreads();
    {
#pragma unroll
        for (int r2 = 0; r2 < 2; r2++) {
            int row = r2 * 8 + (lane >> 3);
            int colg = (lane & 7) * 8;
            float4 a = *(const float4*)&T_s[w][row][colg];
            float4 b = *(const float4*)&T_s[w][row][colg + 4];
            *(bf16x8*)&P[(size_t)(m0 + row) * 256 + w * 64 + colg] = cvt8(a, b);
        }
    }
}

// ---------------------------------------------------------------------------
// Kernel 3: per-edge gather + add + LayerNorm + FiLM + relu.
// Half-wave per edge row; bf16x4 gathers from L2-resident P; nontemporal
// f32x4 output stores keep the 134 MB stream from evicting P in L2.
// XCD-contiguous swizzle: (blk&7)*4096+(blk>>3) gives each XCD a contiguous
// slice of the SORTED edge list.
// ---------------------------------------------------------------------------
__global__ __launch_bounds__(256) void edge_kernel(
    const int* __restrict__ edges, const char* __restrict__ ws,
    const float* __restrict__ b_film, float* __restrict__ out)
{
    const bf16_t* P = (const bf16_t*)(ws + WS_P);
    const float* gamma = (const float*)(ws + WS_GA);
    const float* beta  = (const float*)(ws + WS_BE);

    int t = threadIdx.x;
    int lane = t & 63, wv = t >> 6;
    int v = (blockIdx.x & 7) * 4096 + (blockIdx.x >> 3);
    int r = v * 8 + wv * 2 + (lane >> 5);
    int hl = lane & 31;
    int c = hl * 4;

    int bb = v >> 11;                        // reshape batch, block-uniform
    float4 g4  = *(const float4*)&gamma[bb * 128 + c];
    float4 be4 = *(const float4*)&beta[bb * 128 + c];
    float4 bf4 = *(const float4*)&b_film[c];

    int e = edges[r];
    int ri = e >> 8;
    int rj = ((e >> 16) << 8) | (e & 255);

    bf16x4 p1 = *(const bf16x4*)&P[(size_t)ri * 256 + c];
    bf16x4 p2 = *(const bf16x4*)&P[(size_t)rj * 256 + 128 + c];

    float x0 = (float)p1[0] + (float)p2[0] + bf4.x;
    float x1 = (float)p1[1] + (float)p2[1] + bf4.y;
    float x2 = (float)p1[2] + (float)p2[2] + bf4.z;
    float x3 = (float)p1[3] + (float)p2[3] + bf4.w;

    float s  = x0 + x1 + x2 + x3;
    float ss = x0 * x0 + x1 * x1 + x2 * x2 + x3 * x3;
#pragma unroll
    for (int o = 16; o > 0; o >>= 1) {       // reduce within the 32-lane half
        s  += __shfl_xor(s, o);
        ss += __shfl_xor(ss, o);
    }
    float mu  = s * (1.0f / 128.0f);
    float var = ss * (1.0f / 128.0f) - mu * mu;
    float rs  = rsqrtf(var + 1e-5f);

    f32x4 o4;
    o4[0] = fmaxf((x0 - mu) * rs * g4.x + be4.x, 0.f);
    o4[1] = fmaxf((x1 - mu) * rs * g4.y + be4.y, 0.f);
    o4[2] = fmaxf((x2 - mu) * rs * g4.z + be4.z, 0.f);
    o4[3] = fmaxf((x3 - mu) * rs * g4.w + be4.w, 0.f);
    __builtin_nontemporal_store(o4, (f32x4*)&out[(size_t)r * 128 + c]);
}

extern "C" void kernel_launch(void* const* d_in, const int* in_sizes, int n_in,
                              void* d_out, int out_size, void* d_ws, size_t ws_size,
                              hipStream_t stream) {
    const float* node_feats = (const float*)d_in[0];
    const float* cond_feats = (const float*)d_in[1];
    const int*   edges      = (const int*)d_in[2];
    const float* v_node     = (const float*)d_in[3];
    const float* g_node     = (const float*)d_in[4];
    const float* b_node     = (const float*)d_in[5];
    const float* v_cond     = (const float*)d_in[6];
    const float* g_cond     = (const float*)d_in[7];
    const float* b_cond     = (const float*)d_in[8];
    const float* w_film     = (const float*)d_in[9];
    const float* b_film     = (const float*)d_in[10];
    float* out = (float*)d_out;
    char* ws = (char*)d_ws;

    prep_kernel<<<1104, 256, 0, stream>>>(cond_feats, v_node, g_node,
                                          v_cond, g_cond, b_cond, w_film, ws);
    gemm_kernel<<<256, 256, 0, stream>>>(node_feats, b_node, ws);
    edge_kernel<<<32768, 256, 0, stream>>>(edges, ws, b_film, out);
}

// Round 6
// 193.237 us; speedup vs baseline: 1.0444x; 1.0444x over previous
//
#include <hip/hip_runtime.h>
#include <hip/hip_bf16.h>

typedef __bf16 bf16_t;
typedef bf16_t bf16x8 __attribute__((ext_vector_type(8)));
typedef bf16_t bf16x4 __attribute__((ext_vector_type(4)));
typedef float f32x4 __attribute__((ext_vector_type(4)));

#define NODE_DIM 512
#define COND_DIM 512
#define EDGE_DIM 128

// workspace layout (bytes)
#define WS_A    0x000000   // A_bf16: 4096x512 bf16 = 4 MB
#define WS_WN   0x400000   // v_node bf16: 128x512 = 128 KB
#define WS_WC   0x420000   // w_film bf16 (B^T perm): 256x128 = 64 KB
#define WS_SC   0x430000   // scale_node: 128 f32
#define WS_GA   0x431000   // gamma: 16x128 f32
#define WS_BE   0x433000   // beta: 16x128 f32
#define WS_P    0x440000   // P: 4096x256 bf16 = 2 MB

__device__ __forceinline__ bf16x8 cvt8(float4 a, float4 b) {
    bf16x8 v;
    v[0] = (bf16_t)a.x; v[1] = (bf16_t)a.y; v[2] = (bf16_t)a.z; v[3] = (bf16_t)a.w;
    v[4] = (bf16_t)b.x; v[5] = (bf16_t)b.y; v[6] = (bf16_t)b.z; v[7] = (bf16_t)b.w;
    return v;
}

// ---------------------------------------------------------------------------
// Kernel 1 (prep): fp32->bf16 conversions + weight-norm scales + gamma/beta.
// blocks [0,1024): node_feats -> A_bf16        (2M elems, 8/thread)
// blocks [1024,1056): v_node -> Wn_bf16
// blocks [1056,1072): w_film -> Wc_bf16 permuted (row n<128 = w_film[n][0:128],
//                     row n>=128 = w_film[n-128][128:256])
// blocks [1072,1104): scale_node[e] = g_node[e]/||v_node[e]||  (wave per row)
// blocks [1104,2128): gamma/beta = cond_feats @ weight_norm(v_cond)^T + b_cond
// ---------------------------------------------------------------------------
__global__ __launch_bounds__(256) void prep_kernel(
    const float* __restrict__ node_feats, const float* __restrict__ cond_feats,
    const float* __restrict__ v_node, const float* __restrict__ g_node,
    const float* __restrict__ v_cond, const float* __restrict__ g_cond,
    const float* __restrict__ b_cond, const float* __restrict__ w_film,
    char* __restrict__ ws)
{
    bf16_t* A  = (bf16_t*)(ws + WS_A);
    bf16_t* Wn = (bf16_t*)(ws + WS_WN);
    bf16_t* Wc = (bf16_t*)(ws + WS_WC);
    float* scale_node = (float*)(ws + WS_SC);
    float* gamma = (float*)(ws + WS_GA);
    float* beta  = (float*)(ws + WS_BE);

    int t = threadIdx.x;
    int bid = blockIdx.x;
    int lane = t & 63, wv = t >> 6;

    if (bid < 1024) {
        size_t idx = ((size_t)bid * 256 + t) * 8;
        float4 a = ((const float4*)(node_feats + idx))[0];
        float4 b = ((const float4*)(node_feats + idx))[1];
        *(bf16x8*)(A + idx) = cvt8(a, b);
    } else if (bid < 1056) {
        size_t idx = ((size_t)(bid - 1024) * 256 + t) * 8;
        float4 a = ((const float4*)(v_node + idx))[0];
        float4 b = ((const float4*)(v_node + idx))[1];
        *(bf16x8*)(Wn + idx) = cvt8(a, b);
    } else if (bid < 1072) {
        int u = (bid - 1056) * 256 + t;      // 0..4095, 8 elems each
        int n = u >> 4;                      // 0..255
        int ko = (u & 15) * 8;               // 0..120
        const float* src = (n < 128) ? (w_film + (size_t)n * 256 + ko)
                                     : (w_film + (size_t)(n - 128) * 256 + 128 + ko);
        float4 a = ((const float4*)src)[0];
        float4 b = ((const float4*)src)[1];
        *(bf16x8*)(Wc + (size_t)n * 128 + ko) = cvt8(a, b);
    } else if (bid < 1104) {
        int id = (bid - 1072) * 4 + wv;      // 0..127
        const float* vn = v_node + (size_t)id * NODE_DIM + lane * 8;
        float sq = 0.f;
#pragma unroll
        for (int i = 0; i < 2; i++) {
            float4 v4 = ((const float4*)vn)[i];
            sq += v4.x * v4.x + v4.y * v4.y + v4.z * v4.z + v4.w * v4.w;
        }
#pragma unroll
        for (int o = 32; o > 0; o >>= 1) sq += __shfl_xor(sq, o);
        if (lane == 0) scale_node[id] = g_node[id] * rsqrtf(sq);
    } else {
        int id = (bid - 1104) * 4 + wv;      // 0..4095
        int b = id >> 8, n = id & 255;
        const float* cf = cond_feats + b * COND_DIM + lane * 8;
        const float* vc = v_cond + (size_t)n * COND_DIM + lane * 8;
        float dot = 0.f, sq = 0.f;
#pragma unroll
        for (int i = 0; i < 2; i++) {
            float4 c4 = ((const float4*)cf)[i];
            float4 v4 = ((const float4*)vc)[i];
            dot += c4.x * v4.x + c4.y * v4.y + c4.z * v4.z + c4.w * v4.w;
            sq  += v4.x * v4.x + v4.y * v4.y + v4.z * v4.z + v4.w * v4.w;
        }
#pragma unroll
        for (int o = 32; o > 0; o >>= 1) {
            dot += __shfl_xor(dot, o);
            sq  += __shfl_xor(sq, o);
        }
        if (lane == 0) {
            float val = dot * (g_cond[n] * rsqrtf(sq)) + b_cond[n];
            if (n < 128) gamma[b * 128 + n] = val + 1.0f;
            else         beta[b * 128 + (n - 128)] = val;
        }
    }
}

// ---------------------------------------------------------------------------
// Kernel 2 (gemm): 256 blocks x 16-row M-tiles, 4 waves.
// Fragments load DIRECTLY from global bf16 in MFMA layout (no LDS staging,
// no barriers in the K-loop): lane l holds X[row=l&15][k=(l>>4)*8+j].
// A wave's 16-B/lane load touches 16 rows x 64 B = 16 full cache lines.
// Phase 1: nodes16x128 = relu((A16x512 @ Wn^T)*scale + b_node) -> LDS bf16.
// Phase 2: P16x256 = nodes @ Wc^T; epilogue transposes C-layout via LDS and
// stores P with 16-B coalesced writes.
// ---------------------------------------------------------------------------
__global__ __launch_bounds__(256) void gemm_kernel(
    const float* __restrict__ b_node, char* __restrict__ ws)
{
    const bf16_t* A  = (const bf16_t*)(ws + WS_A);
    const bf16_t* Wn = (const bf16_t*)(ws + WS_WN);
    const bf16_t* Wc = (const bf16_t*)(ws + WS_WC);
    const float* scale_node = (const float*)(ws + WS_SC);
    bf16_t* P = (bf16_t*)(ws + WS_P);

    __shared__ __attribute__((aligned(16))) bf16_t N_s[16 * 136];
    __shared__ __attribute__((aligned(16))) float  T_s[4][16][68];

    int t = threadIdx.x;
    int lane = t & 63, w = t >> 6;
    int r16 = lane & 15, half = lane >> 4;
    int m0 = blockIdx.x * 16;

    f32x4 zero4 = {0.f, 0.f, 0.f, 0.f};

    // ---- phase 1: wave w covers output cols [w*32, w*32+32) ----
    f32x4 acc0 = zero4, acc1 = zero4;
    {
        const bf16_t* aptr = A + (size_t)(m0 + r16) * NODE_DIM + half * 8;
        const bf16_t* bptr = Wn + (size_t)(w * 32 + r16) * NODE_DIM + half * 8;
#pragma unroll
        for (int ks = 0; ks < 16; ks++) {
            bf16x8 af = *(const bf16x8*)(aptr + ks * 32);
            bf16x8 b0 = *(const bf16x8*)(bptr + ks * 32);
            bf16x8 b1 = *(const bf16x8*)(bptr + 16 * NODE_DIM + ks * 32);
            acc0 = __builtin_amdgcn_mfma_f32_16x16x32_bf16(af, b0, acc0, 0, 0, 0);
            acc1 = __builtin_amdgcn_mfma_f32_16x16x32_bf16(af, b1, acc1, 0, 0, 0);
        }
    }
    // epilogue 1: C/D layout col=lane&15, row=(lane>>4)*4+reg -> N_s[row][col]
    {
        int rbase = half * 4;
#pragma unroll
        for (int j = 0; j < 2; j++) {
            int col = w * 32 + j * 16 + r16;
            float s = scale_node[col], bb = b_node[col];
            f32x4 a = j ? acc1 : acc0;
#pragma unroll
            for (int r = 0; r < 4; r++) {
                float v = fmaxf(a[r] * s + bb, 0.f);
                N_s[(rbase + r) * 136 + col] = (bf16_t)v;
            }
        }
    }
    __syncthreads();

    // ---- phase 2: wave w covers output cols [w*64, w*64+64) ----
    f32x4 acc2[4];
#pragma unroll
    for (int i = 0; i < 4; i++) acc2[i] = zero4;
    {
        const bf16_t* bptr = Wc + (size_t)(w * 64 + r16) * 128 + half * 8;
#pragma unroll
        for (int ks = 0; ks < 4; ks++) {
            bf16x8 af = *(const bf16x8*)&N_s[r16 * 136 + ks * 32 + half * 8];
#pragma unroll
            for (int j = 0; j < 4; j++) {
                bf16x8 bf = *(const bf16x8*)(bptr + j * 16 * 128 + ks * 32);
                acc2[j] = __builtin_amdgcn_mfma_f32_16x16x32_bf16(af, bf, acc2[j], 0, 0, 0);
            }
        }
    }
    // epilogue 2: transpose via LDS, then 16-B coalesced bf16 stores to P
    {
        int rbase = half * 4;
#pragma unroll
        for (int j = 0; j < 4; j++) {
            int col = j * 16 + r16;
#pragma unroll
            for (int r = 0; r < 4; r++) T_s[w][rbase + r][col] = acc2[j][r];
        }
    }
    __syncthreads();
    {
#pragma unroll
        for (int r2 = 0; r2 < 2; r2++) {
            int row = r2 * 8 + (lane >> 3);
            int colg = (lane & 7) * 8;
            float4 a = *(const float4*)&T_s[w][row][colg];
            float4 b = *(const float4*)&T_s[w][row][colg + 4];
            *(bf16x8*)&P[(size_t)(m0 + row) * 256 + w * 64 + colg] = cvt8(a, b);
        }
    }
}

// ---------------------------------------------------------------------------
// Kernel 3: per-edge gather + add + LayerNorm + FiLM + relu.
// Half-wave (32 lanes) per edge row; bf16x4 gathers from L2-resident P;
// float4 coalesced output stores. XCD-contiguous swizzle: (blk&7)*4096+
// (blk>>3) gives each XCD a contiguous slice of the SORTED edge list.
// e = b*65536 + i*256 + j  =>  row_i = e>>8 ; row_j = (e>>16)<<8 | (e&255)
// gamma/beta batch = edge_row >> 14 (uniform per block since 8 | 16384)
// ---------------------------------------------------------------------------
__global__ __launch_bounds__(256) void edge_kernel(
    const int* __restrict__ edges, const char* __restrict__ ws,
    const float* __restrict__ b_film, float* __restrict__ out)
{
    const bf16_t* P = (const bf16_t*)(ws + WS_P);
    const float* gamma = (const float*)(ws + WS_GA);
    const float* beta  = (const float*)(ws + WS_BE);

    int t = threadIdx.x;
    int lane = t & 63, wv = t >> 6;
    int v = (blockIdx.x & 7) * 4096 + (blockIdx.x >> 3);
    int r = v * 8 + wv * 2 + (lane >> 5);
    int hl = lane & 31;
    int c = hl * 4;

    int bb = v >> 11;                        // reshape batch, block-uniform
    float4 g4  = *(const float4*)&gamma[bb * 128 + c];
    float4 be4 = *(const float4*)&beta[bb * 128 + c];
    float4 bf4 = *(const float4*)&b_film[c];

    int e = edges[r];
    int ri = e >> 8;
    int rj = ((e >> 16) << 8) | (e & 255);

    bf16x4 p1 = *(const bf16x4*)&P[(size_t)ri * 256 + c];
    bf16x4 p2 = *(const bf16x4*)&P[(size_t)rj * 256 + 128 + c];

    float x0 = (float)p1[0] + (float)p2[0] + bf4.x;
    float x1 = (float)p1[1] + (float)p2[1] + bf4.y;
    float x2 = (float)p1[2] + (float)p2[2] + bf4.z;
    float x3 = (float)p1[3] + (float)p2[3] + bf4.w;

    float s  = x0 + x1 + x2 + x3;
    float ss = x0 * x0 + x1 * x1 + x2 * x2 + x3 * x3;
#pragma unroll
    for (int o = 16; o > 0; o >>= 1) {       // reduce within the 32-lane half
        s  += __shfl_xor(s, o);
        ss += __shfl_xor(ss, o);
    }
    float mu  = s * (1.0f / 128.0f);
    float var = ss * (1.0f / 128.0f) - mu * mu;
    float rs  = rsqrtf(var + 1e-5f);

    float4 o4;
    o4.x = fmaxf((x0 - mu) * rs * g4.x + be4.x, 0.f);
    o4.y = fmaxf((x1 - mu) * rs * g4.y + be4.y, 0.f);
    o4.z = fmaxf((x2 - mu) * rs * g4.z + be4.z, 0.f);
    o4.w = fmaxf((x3 - mu) * rs * g4.w + be4.w, 0.f);
    *(float4*)&out[(size_t)r * 128 + c] = o4;
}

extern "C" void kernel_launch(void* const* d_in, const int* in_sizes, int n_in,
                              void* d_out, int out_size, void* d_ws, size_t ws_size,
                              hipStream_t stream) {
    const float* node_feats = (const float*)d_in[0];
    const float* cond_feats = (const float*)d_in[1];
    const int*   edges      = (const int*)d_in[2];
    const float* v_node     = (const float*)d_in[3];
    const float* g_node     = (const float*)d_in[4];
    const float* b_node     = (const float*)d_in[5];
    const float* v_cond     = (const float*)d_in[6];
    const float* g_cond     = (const float*)d_in[7];
    const float* b_cond     = (const float*)d_in[8];
    const float* w_film     = (const float*)d_in[9];
    const float* b_film     = (const float*)d_in[10];
    float* out = (float*)d_out;
    char* ws = (char*)d_ws;

    prep_kernel<<<2128, 256, 0, stream>>>(node_feats, cond_feats, v_node, g_node,
                                          v_cond, g_cond, b_cond, w_film, ws);
    gemm_kernel<<<256, 256, 0, stream>>>(b_node, ws);
    edge_kernel<<<32768, 256, 0, stream>>>(edges, ws, b_film, out);
}